// Round 11
// baseline (169.610 us; speedup 1.0000x reference)
//
#include <hip/hip_runtime.h>

#define N_NODES 100000
#define IN_CH 128
#define HID_CH 256
#define OUT_CH 128
#define N_EDGES 1600000

#define NBK 782                                   // ceil(N_NODES/128) buckets of 128 nodes
#define BIN_BLOCKS 256
#define EPB (N_EDGES / BIN_BLOCKS)                // 6250 edges per bin block

typedef __attribute__((ext_vector_type(8))) short short8;
typedef __attribute__((ext_vector_type(4))) float f32x4;

// bf16 <-> f32 helpers (bit ops; finite data only)
__device__ __forceinline__ float b2f(ushort u) {
    unsigned int x = ((unsigned int)u) << 16;
    return __uint_as_float(x);
}
__device__ __forceinline__ ushort f2b(float f) {
    unsigned int u = __float_as_uint(f);
    u += 0x7FFFu + ((u >> 16) & 1u);   // round-to-nearest-even
    return (ushort)(u >> 16);
}

// ---------------------------------------------------------------------------
// Prep (+ fused ghist): x fp32 -> xb bf16 ; W1 -> W1T ; W2 -> W2T ;
// last 256 blocks: per-(block,bucket) dst histogram (transposed store).
// ---------------------------------------------------------------------------
#define PREP_X_BLOCKS 6250
#define PREP_W1_BLOCKS 128
#define PREP_W2_BLOCKS 128
#define PREP_TOTAL (PREP_X_BLOCKS + PREP_W1_BLOCKS + PREP_W2_BLOCKS)
__global__ __launch_bounds__(256) void prep_kernel(
    const float* __restrict__ x, const float* __restrict__ W1,
    const float* __restrict__ W2, const int* __restrict__ dst,
    ushort* __restrict__ xb, ushort* __restrict__ W1T,
    ushort* __restrict__ W2T, int* __restrict__ histT) {
    const int b = blockIdx.x;
    const int t = threadIdx.x;
    if (b < PREP_X_BLOCKS) {
        const size_t i = (size_t)b * 2048 + t * 8;
        float4 a = *reinterpret_cast<const float4*>(x + i);
        float4 c = *reinterpret_cast<const float4*>(x + i + 4);
        ushort v[8] = {f2b(a.x), f2b(a.y), f2b(a.z), f2b(a.w),
                       f2b(c.x), f2b(c.y), f2b(c.z), f2b(c.w)};
        *reinterpret_cast<short8*>(xb + i) = *reinterpret_cast<short8*>(v);
    } else if (b < PREP_X_BLOCKS + PREP_W1_BLOCKS) {
        const int i = (b - PREP_X_BLOCKS) * 256 + t;     // oc*128 + k
        const int oc = i >> 7, k = i & 127;
        W1T[i] = f2b(W1[k * HID_CH + oc]);
    } else if (b < PREP_TOTAL) {
        const int i = (b - PREP_X_BLOCKS - PREP_W1_BLOCKS) * 256 + t; // oc*256+k
        const int oc = i >> 8, k = i & 255;
        W2T[i] = f2b(W2[k * OUT_CH + oc]);
    } else {
        __shared__ int h[NBK];
        const int bb = b - PREP_TOTAL;
        for (int k = t; k < NBK; k += 256) h[k] = 0;
        __syncthreads();
        const int base = bb * EPB;
        for (int i = t; i < EPB; i += 256)
            atomicAdd(&h[dst[base + i] >> 7], 1);
        __syncthreads();
        for (int k = t; k < NBK; k += 256) histT[k * BIN_BLOCKS + bb] = h[k];
    }
}

// ---------------------------------------------------------------------------
// Bucketing step 2a: per-bucket exclusive scan over the 256 block counts.
// ---------------------------------------------------------------------------
__global__ __launch_bounds__(256) void scanA_kernel(
    const int* __restrict__ histT, int* __restrict__ blockBaseP,
    int* __restrict__ bktTotal) {
    __shared__ int ts[256];
    const int bk = blockIdx.x, t = threadIdx.x;
    const int v = histT[bk * BIN_BLOCKS + t];
    ts[t] = v;
    __syncthreads();
    #pragma unroll
    for (int o = 1; o < 256; o <<= 1) {
        int add = (t >= o) ? ts[t - o] : 0;
        __syncthreads();
        ts[t] += add;
        __syncthreads();
    }
    blockBaseP[bk * BIN_BLOCKS + t] = ts[t] - v;
    if (t == 255) bktTotal[bk] = ts[255];
}

// ---------------------------------------------------------------------------
// Bucketing step 2b: exclusive scan of the 782 bucket totals (1 block).
// ---------------------------------------------------------------------------
__global__ __launch_bounds__(1024) void scanB_kernel(
    const int* __restrict__ bktTotal, int* __restrict__ bktBase) {
    __shared__ int ts[1024];
    const int t = threadIdx.x;
    const int v = (t < NBK) ? bktTotal[t] : 0;
    ts[t] = v;
    __syncthreads();
    #pragma unroll
    for (int o = 1; o < 1024; o <<= 1) {
        int add = (t >= o) ? ts[t - o] : 0;
        __syncthreads();
        ts[t] += add;
        __syncthreads();
    }
    if (t < NBK) bktBase[t] = ts[t] - v;
}

// ---------------------------------------------------------------------------
// Bucketing step 3: scatter packed entries (dl<<17 | src) into per-block
// contiguous runs inside each bucket region. LDS cursors only.
// ---------------------------------------------------------------------------
__global__ __launch_bounds__(256) void bin_kernel(
    const int* __restrict__ src, const int* __restrict__ dst,
    const int* __restrict__ blockBaseP, const int* __restrict__ bktBase,
    unsigned int* __restrict__ ebuf) {
    __shared__ int base[NBK];
    __shared__ int cur[NBK];
    const int b = blockIdx.x, t = threadIdx.x;
    for (int k = t; k < NBK; k += 256) {
        base[k] = bktBase[k] + blockBaseP[k * BIN_BLOCKS + b];
        cur[k] = 0;
    }
    __syncthreads();
    const int ebase = b * EPB;
    for (int i = t; i < EPB; i += 256) {
        const int d = dst[ebase + i];
        const int s = src[ebase + i];
        const int bk = d >> 7;
        const int r = atomicAdd(&cur[bk], 1);
        ebuf[base[bk] + r] = ((unsigned int)(d & 127) << 17) | (unsigned int)s;
    }
}

// ---------------------------------------------------------------------------
// Bucketing step 4: node-sort each bucket -> exact CSR (global csr_src/offs).
// ---------------------------------------------------------------------------
__global__ __launch_bounds__(256) void group_kernel(
    const unsigned int* __restrict__ ebuf,
    const int* __restrict__ bktBase, const int* __restrict__ bktTotal,
    int* __restrict__ csr_src, int* __restrict__ offs) {
    __shared__ int hist[128];
    __shared__ int cur[128];
    const int bk = blockIdx.x, t = threadIdx.x;
    if (t < 128) hist[t] = 0;
    __syncthreads();
    const int start = bktBase[bk];
    const int cnt   = bktTotal[bk];
    for (int i = t; i < cnt; i += 256)
        atomicAdd(&hist[ebuf[start + i] >> 17], 1);
    __syncthreads();
    int v = (t < 128) ? hist[t] : 0;
    #pragma unroll
    for (int o = 1; o < 128; o <<= 1) {
        int add = (t < 128 && t >= o) ? hist[t - o] : 0;
        __syncthreads();
        if (t < 128) hist[t] += add;
        __syncthreads();
    }
    if (t < 128) {
        const int excl = hist[t] - v;
        cur[t] = excl;
        const int node = bk * 128 + t;
        if (node < N_NODES) offs[node] = start + excl;
    }
    if (bk == 0 && t == 0) offs[N_NODES] = N_EDGES;
    __syncthreads();
    for (int i = t; i < cnt; i += 256) {
        const unsigned int e = ebuf[start + i];
        const int dl = e >> 17;
        const int p = atomicAdd(&cur[dl], 1);
        csr_src[start + p] = (int)(e & 0x1FFFF);
    }
}

// ---------------------------------------------------------------------------
// Gather-aggregate fused with GIN self-term (bf16 rows, fp32 accum):
//   h_in[i] = bf16( (1+eps)*x[i] + sum_{j in N(i)} x[j] )
// ONE NODE PER WAVE: lane = slice(l>>4) x channel(l&15, short8 = 16 B).
// One load instruction fetches 4 full 256 B rows; two 4-edge subtiles in
// flight (8 independent row loads/wave); zero exec-mask divergence.
// Final: cross-slice shfl_xor reduce, lanes 0-15 store the 256 B row.
// ---------------------------------------------------------------------------
__global__ __launch_bounds__(256) void gather_kernel(
    const ushort* __restrict__ xb,
    const float* __restrict__ eps_p,
    const int* __restrict__ offs,
    const int* __restrict__ csr_src,
    ushort* __restrict__ h_in) {
    const int node = blockIdx.x * 4 + (threadIdx.x >> 6);
    const int l = threadIdx.x & 63;
    const int slice = l >> 4;          // 0..3 edge slot
    const int c = (l & 15) * 8;        // 8 channels per lane
    const int beg = offs[node];
    const int end = offs[node + 1];

    float a0[8], a1[8];
    #pragma unroll
    for (int j = 0; j < 8; ++j) { a0[j] = 0.f; a1[j] = 0.f; }

    int base = beg;
    for (; base + 8 <= end; base += 8) {
        const int sidx = csr_src[base + (l & 7)];
        const int sA = __shfl(sidx, slice, 64);        // edges base+0..3
        const int sB = __shfl(sidx, 4 + slice, 64);    // edges base+4..7
        short8 vA = *reinterpret_cast<const short8*>(xb + (size_t)sA * IN_CH + c);
        short8 vB = *reinterpret_cast<const short8*>(xb + (size_t)sB * IN_CH + c);
        #pragma unroll
        for (int j = 0; j < 8; ++j) {
            a0[j] += b2f((ushort)vA[j]);
            a1[j] += b2f((ushort)vB[j]);
        }
    }
    const int r = end - base;          // 0..7 remainder
    if (r > 0) {
        const int sidx = csr_src[base + min(l & 7, r - 1)];
        const int sA = __shfl(sidx, min(slice, r - 1), 64);
        const int sB = __shfl(sidx, min(4 + slice, r - 1), 64);
        if (slice < r) {
            short8 vA = *reinterpret_cast<const short8*>(xb + (size_t)sA * IN_CH + c);
            #pragma unroll
            for (int j = 0; j < 8; ++j) a0[j] += b2f((ushort)vA[j]);
        }
        if (4 + slice < r) {
            short8 vB = *reinterpret_cast<const short8*>(xb + (size_t)sB * IN_CH + c);
            #pragma unroll
            for (int j = 0; j < 8; ++j) a1[j] += b2f((ushort)vB[j]);
        }
    }

    // cross-slice reduction: slices 0-3 hold partials of the same channels
    #pragma unroll
    for (int j = 0; j < 8; ++j) {
        a0[j] += a1[j];
        a0[j] += __shfl_xor(a0[j], 16, 64);
        a0[j] += __shfl_xor(a0[j], 32, 64);
    }

    if (l < 16) {
        const float scale = 1.0f + eps_p[0];
        short8 sv = *reinterpret_cast<const short8*>(xb + (size_t)node * IN_CH + c);
        ushort o[8];
        #pragma unroll
        for (int j = 0; j < 8; ++j)
            o[j] = f2b(scale * b2f((ushort)sv[j]) + a0[j]);
        *reinterpret_cast<short8*>(h_in + (size_t)node * IN_CH + c) =
            *reinterpret_cast<short8*>(o);
    }
}

// ---------------------------------------------------------------------------
// Fused MLP (MFMA): out = log_softmax(relu(relu(h_in@W1+b1)@W2+b2))
// 512 thr = 8 waves x 16 rows = 128 rows/block. W1T staged into a 64 KB
// XOR-swizzled LDS buffer (re-staged with W2T after phase 1); h1 parked in
// per-wave padded LDS tiles.
// ---------------------------------------------------------------------------
#define H1_LD 264          // padded h1 row stride in halves
__global__ __launch_bounds__(512) void mlp_fused(
    const ushort* __restrict__ h_in,
    const ushort* __restrict__ W1T,
    const ushort* __restrict__ W2T,
    const float* __restrict__ b1,
    const float* __restrict__ b2,
    float* __restrict__ out) {
    __shared__ ushort wbuf[32768];            // 64 KB weights (W1T, then W2T)
    __shared__ ushort h1s[8][16 * H1_LD];     // 67.6 KB h1 tiles
    const int t    = threadIdx.x;
    const int w    = t >> 6;
    const int lane = t & 63;
    const int lr   = lane & 15;
    const int lk   = lane >> 4;
    const int row0 = blockIdx.x * 128 + w * 16;
    const int arow = row0 + lr;
    const int arc  = arow < N_NODES ? arow : N_NODES - 1;
    ushort* tile = h1s[w];
    const int sw = (lr & 7) << 3;             // read-side swizzle (halves)

    // ---- stage W1T (rows of 128 halves, swizzled); 64 halves/thread ----
    {
        const ushort* gw = W1T + t * 64;
        const int row = t >> 1;
        const int s = (row & 7) << 3;
        ushort* dstp = wbuf + row * 128;
        #pragma unroll
        for (int j = 0; j < 8; ++j) {
            short8 v = *reinterpret_cast<const short8*>(gw + j * 8);
            const int col = (t & 1) * 64 + j * 8;
            *reinterpret_cast<short8*>(dstp + (col ^ s)) = v;
        }
    }

    // A-frags for phase 1 (global h_in, L2-resident)
    short8 a[4];
    const ushort* ap = h_in + (size_t)arc * IN_CH + lk * 8;
    #pragma unroll
    for (int kk = 0; kk < 4; ++kk)
        a[kk] = *reinterpret_cast<const short8*>(ap + kk * 32);

    __syncthreads();

    // ---- phase 1: h1 = relu(h_in @ W1 + b1), 16 rows x 256 cols ----
    #pragma unroll
    for (int ct = 0; ct < 16; ++ct) {
        const ushort* bp = wbuf + (ct * 16 + lr) * 128;
        f32x4 acc = (f32x4){0.f, 0.f, 0.f, 0.f};
        #pragma unroll
        for (int kk = 0; kk < 4; ++kk) {
            short8 b = *reinterpret_cast<const short8*>(bp + ((lk * 8 + kk * 32) ^ sw));
            acc = __builtin_amdgcn_mfma_f32_16x16x32_bf16(a[kk], b, acc, 0, 0, 0);
        }
        const float bb = b1[ct * 16 + lr];
        #pragma unroll
        for (int r = 0; r < 4; ++r) {
            float v = fmaxf(acc[r] + bb, 0.0f);
            tile[(lk * 4 + r) * H1_LD + ct * 16 + lr] = f2b(v);
        }
    }

    __syncthreads();   // all waves done reading W1 from wbuf

    // ---- stage W2T (rows of 256 halves, swizzled) ----
    {
        const ushort* gw = W2T + t * 64;
        const int row = t >> 2;
        const int s = (row & 7) << 3;
        ushort* dstp = wbuf + row * 256;
        #pragma unroll
        for (int j = 0; j < 8; ++j) {
            short8 v = *reinterpret_cast<const short8*>(gw + j * 8);
            const int col = (t & 3) * 64 + j * 8;
            *reinterpret_cast<short8*>(dstp + (col ^ s)) = v;
        }
    }

    // A2-frags from own (wave-private) tile — safe before the barrier
    short8 a2[8];
    #pragma unroll
    for (int kk = 0; kk < 8; ++kk)
        a2[kk] = *reinterpret_cast<const short8*>(tile + lr * H1_LD + lk * 8 + kk * 32);

    __syncthreads();   // W2 staged

    // ---- phase 2: out = lsm(relu(h1 @ W2 + b2)), 16 rows x 128 cols ----
    f32x4 acc2[8];
    #pragma unroll
    for (int ct = 0; ct < 8; ++ct) acc2[ct] = (f32x4){0.f, 0.f, 0.f, 0.f};

    #pragma unroll
    for (int ct = 0; ct < 8; ++ct) {
        const ushort* bp = wbuf + (ct * 16 + lr) * 256;
        #pragma unroll
        for (int kk = 0; kk < 8; ++kk) {
            short8 b = *reinterpret_cast<const short8*>(bp + ((lk * 8 + kk * 32) ^ sw));
            acc2[ct] = __builtin_amdgcn_mfma_f32_16x16x32_bf16(a2[kk], b, acc2[ct], 0, 0, 0);
        }
    }

    float bias[8];
    #pragma unroll
    for (int ct = 0; ct < 8; ++ct) bias[ct] = b2[ct * 16 + lr];

    const int orow0 = row0 + lk * 4;
    #pragma unroll
    for (int r = 0; r < 4; ++r) {
        float v[8];
        float m = -1e30f;
        #pragma unroll
        for (int ct = 0; ct < 8; ++ct) {
            v[ct] = fmaxf(acc2[ct][r] + bias[ct], 0.0f);
            m = fmaxf(m, v[ct]);
        }
        #pragma unroll
        for (int o = 1; o < 16; o <<= 1) m = fmaxf(m, __shfl_xor(m, o));
        float s = 0.0f;
        #pragma unroll
        for (int ct = 0; ct < 8; ++ct) s += __expf(v[ct] - m);
        #pragma unroll
        for (int o = 1; o < 16; o <<= 1) s += __shfl_xor(s, o);
        const float lse = m + __logf(s);
        const int orow = orow0 + r;
        if (orow < N_NODES) {
            #pragma unroll
            for (int ct = 0; ct < 8; ++ct)
                out[(size_t)orow * OUT_CH + ct * 16 + lr] = v[ct] - lse;
        }
    }
}

extern "C" void kernel_launch(void* const* d_in, const int* in_sizes, int n_in,
                              void* d_out, int out_size, void* d_ws, size_t ws_size,
                              hipStream_t stream) {
    const float* x    = (const float*)d_in[0];
    const int*   ei   = (const int*)d_in[1];
    const float* W1   = (const float*)d_in[2];
    const float* b1   = (const float*)d_in[3];
    const float* W2   = (const float*)d_in[4];
    const float* b2   = (const float*)d_in[5];
    const float* eps  = (const float*)d_in[6];
    float* out = (float*)d_out;

    // workspace layout
    ushort* xb   = (ushort*)d_ws;                          // 12.8M ushort
    ushort* h_in = xb + (size_t)N_NODES * IN_CH;           // 12.8M
    ushort* W1T  = h_in + (size_t)N_NODES * IN_CH;         // 32768
    ushort* W2T  = W1T + IN_CH * HID_CH;                   // 32768
    int* histT      = (int*)(W2T + HID_CH * OUT_CH);       // NBK*256
    int* blockBaseP = histT + NBK * BIN_BLOCKS;            // NBK*256
    int* bktTotal   = blockBaseP + NBK * BIN_BLOCKS;       // NBK
    int* bktBase    = bktTotal + NBK;                      // NBK
    int* offs       = bktBase + NBK;                       // N_NODES+1
    unsigned int* ebuf = (unsigned int*)(offs + N_NODES + 2); // 1.6M
    int* csr_src    = (int*)(ebuf + N_EDGES);              // 1.6M

    const int* src = ei;
    const int* dst = ei + N_EDGES;

    prep_kernel<<<PREP_TOTAL + BIN_BLOCKS, 256, 0, stream>>>(
        x, W1, W2, dst, xb, W1T, W2T, histT);
    scanA_kernel<<<NBK, 256, 0, stream>>>(histT, blockBaseP, bktTotal);
    scanB_kernel<<<1, 1024, 0, stream>>>(bktTotal, bktBase);
    bin_kernel<<<BIN_BLOCKS, 256, 0, stream>>>(src, dst, blockBaseP, bktBase, ebuf);
    group_kernel<<<NBK, 256, 0, stream>>>(ebuf, bktBase, bktTotal, csr_src, offs);
    gather_kernel<<<N_NODES / 4, 256, 0, stream>>>(xb, eps, offs, csr_src, h_in);
    mlp_fused<<<(N_NODES + 127) / 128, 512, 0, stream>>>(h_in, W1T, W2T, b1, b2, out);
}

// Round 12
// 163.518 us; speedup vs baseline: 1.0373x; 1.0373x over previous
//
#include <hip/hip_runtime.h>

#define N_NODES 100000
#define IN_CH 128
#define HID_CH 256
#define OUT_CH 128
#define N_EDGES 1600000

#define NBK 782                                   // ceil(N_NODES/128) buckets of 128 nodes
#define BIN_BLOCKS 256
#define EPB (N_EDGES / BIN_BLOCKS)                // 6250 edges per bin block

typedef __attribute__((ext_vector_type(8))) short short8;
typedef __attribute__((ext_vector_type(4))) float f32x4;

// bf16 <-> f32 helpers (bit ops; finite data only)
__device__ __forceinline__ float b2f(ushort u) {
    unsigned int x = ((unsigned int)u) << 16;
    return __uint_as_float(x);
}
__device__ __forceinline__ ushort f2b(float f) {
    unsigned int u = __float_as_uint(f);
    u += 0x7FFFu + ((u >> 16) & 1u);   // round-to-nearest-even
    return (ushort)(u >> 16);
}

// ---------------------------------------------------------------------------
// Prep (+ fused ghist): x fp32 -> xb bf16 ; W1 -> W1T ; W2 -> W2T ;
// last 256 blocks: per-(block,bucket) dst histogram (transposed store).
// ---------------------------------------------------------------------------
#define PREP_X_BLOCKS 6250
#define PREP_W1_BLOCKS 128
#define PREP_W2_BLOCKS 128
#define PREP_TOTAL (PREP_X_BLOCKS + PREP_W1_BLOCKS + PREP_W2_BLOCKS)
__global__ __launch_bounds__(256) void prep_kernel(
    const float* __restrict__ x, const float* __restrict__ W1,
    const float* __restrict__ W2, const int* __restrict__ dst,
    ushort* __restrict__ xb, ushort* __restrict__ W1T,
    ushort* __restrict__ W2T, int* __restrict__ histT) {
    const int b = blockIdx.x;
    const int t = threadIdx.x;
    if (b < PREP_X_BLOCKS) {
        const size_t i = (size_t)b * 2048 + t * 8;
        float4 a = *reinterpret_cast<const float4*>(x + i);
        float4 c = *reinterpret_cast<const float4*>(x + i + 4);
        ushort v[8] = {f2b(a.x), f2b(a.y), f2b(a.z), f2b(a.w),
                       f2b(c.x), f2b(c.y), f2b(c.z), f2b(c.w)};
        *reinterpret_cast<short8*>(xb + i) = *reinterpret_cast<short8*>(v);
    } else if (b < PREP_X_BLOCKS + PREP_W1_BLOCKS) {
        const int i = (b - PREP_X_BLOCKS) * 256 + t;     // oc*128 + k
        const int oc = i >> 7, k = i & 127;
        W1T[i] = f2b(W1[k * HID_CH + oc]);
    } else if (b < PREP_TOTAL) {
        const int i = (b - PREP_X_BLOCKS - PREP_W1_BLOCKS) * 256 + t; // oc*256+k
        const int oc = i >> 8, k = i & 255;
        W2T[i] = f2b(W2[k * OUT_CH + oc]);
    } else {
        __shared__ int h[NBK];
        const int bb = b - PREP_TOTAL;
        for (int k = t; k < NBK; k += 256) h[k] = 0;
        __syncthreads();
        const int base = bb * EPB;
        for (int i = t; i < EPB; i += 256)
            atomicAdd(&h[dst[base + i] >> 7], 1);
        __syncthreads();
        for (int k = t; k < NBK; k += 256) histT[k * BIN_BLOCKS + bb] = h[k];
    }
}

// ---------------------------------------------------------------------------
// Bucketing step 2a: per-bucket exclusive scan over the 256 block counts.
// ---------------------------------------------------------------------------
__global__ __launch_bounds__(256) void scanA_kernel(
    const int* __restrict__ histT, int* __restrict__ blockBaseP,
    int* __restrict__ bktTotal) {
    __shared__ int ts[256];
    const int bk = blockIdx.x, t = threadIdx.x;
    const int v = histT[bk * BIN_BLOCKS + t];
    ts[t] = v;
    __syncthreads();
    #pragma unroll
    for (int o = 1; o < 256; o <<= 1) {
        int add = (t >= o) ? ts[t - o] : 0;
        __syncthreads();
        ts[t] += add;
        __syncthreads();
    }
    blockBaseP[bk * BIN_BLOCKS + t] = ts[t] - v;
    if (t == 255) bktTotal[bk] = ts[255];
}

// ---------------------------------------------------------------------------
// Bucketing step 2b: exclusive scan of the 782 bucket totals (1 block).
// ---------------------------------------------------------------------------
__global__ __launch_bounds__(1024) void scanB_kernel(
    const int* __restrict__ bktTotal, int* __restrict__ bktBase) {
    __shared__ int ts[1024];
    const int t = threadIdx.x;
    const int v = (t < NBK) ? bktTotal[t] : 0;
    ts[t] = v;
    __syncthreads();
    #pragma unroll
    for (int o = 1; o < 1024; o <<= 1) {
        int add = (t >= o) ? ts[t - o] : 0;
        __syncthreads();
        ts[t] += add;
        __syncthreads();
    }
    if (t < NBK) bktBase[t] = ts[t] - v;
}

// ---------------------------------------------------------------------------
// Bucketing step 3: scatter packed entries (dl<<17 | src) into per-block
// contiguous runs inside each bucket region. LDS cursors only.
// ---------------------------------------------------------------------------
__global__ __launch_bounds__(256) void bin_kernel(
    const int* __restrict__ src, const int* __restrict__ dst,
    const int* __restrict__ blockBaseP, const int* __restrict__ bktBase,
    unsigned int* __restrict__ ebuf) {
    __shared__ int base[NBK];
    __shared__ int cur[NBK];
    const int b = blockIdx.x, t = threadIdx.x;
    for (int k = t; k < NBK; k += 256) {
        base[k] = bktBase[k] + blockBaseP[k * BIN_BLOCKS + b];
        cur[k] = 0;
    }
    __syncthreads();
    const int ebase = b * EPB;
    for (int i = t; i < EPB; i += 256) {
        const int d = dst[ebase + i];
        const int s = src[ebase + i];
        const int bk = d >> 7;
        const int r = atomicAdd(&cur[bk], 1);
        ebuf[base[bk] + r] = ((unsigned int)(d & 127) << 17) | (unsigned int)s;
    }
}

// ---------------------------------------------------------------------------
// Bucketing step 4: node-sort each bucket -> exact CSR (global csr_src/offs).
// ---------------------------------------------------------------------------
__global__ __launch_bounds__(256) void group_kernel(
    const unsigned int* __restrict__ ebuf,
    const int* __restrict__ bktBase, const int* __restrict__ bktTotal,
    int* __restrict__ csr_src, int* __restrict__ offs) {
    __shared__ int hist[128];
    __shared__ int cur[128];
    const int bk = blockIdx.x, t = threadIdx.x;
    if (t < 128) hist[t] = 0;
    __syncthreads();
    const int start = bktBase[bk];
    const int cnt   = bktTotal[bk];
    for (int i = t; i < cnt; i += 256)
        atomicAdd(&hist[ebuf[start + i] >> 17], 1);
    __syncthreads();
    int v = (t < 128) ? hist[t] : 0;
    #pragma unroll
    for (int o = 1; o < 128; o <<= 1) {
        int add = (t < 128 && t >= o) ? hist[t - o] : 0;
        __syncthreads();
        if (t < 128) hist[t] += add;
        __syncthreads();
    }
    if (t < 128) {
        const int excl = hist[t] - v;
        cur[t] = excl;
        const int node = bk * 128 + t;
        if (node < N_NODES) offs[node] = start + excl;
    }
    if (bk == 0 && t == 0) offs[N_NODES] = N_EDGES;
    __syncthreads();
    for (int i = t; i < cnt; i += 256) {
        const unsigned int e = ebuf[start + i];
        const int dl = e >> 17;
        const int p = atomicAdd(&cur[dl], 1);
        csr_src[start + p] = (int)(e & 0x1FFFF);
    }
}

// ---------------------------------------------------------------------------
// Gather-aggregate fused with GIN self-term (bf16 rows, fp32 accum):
//   h_in[i] = bf16( (1+eps)*x[i] + sum_{j in N(i)} x[j] )
// One node per wave: lane = slice(l>>4) x channel(l&15, short8 = 16 B).
// ---------------------------------------------------------------------------
__global__ __launch_bounds__(256) void gather_kernel(
    const ushort* __restrict__ xb,
    const float* __restrict__ eps_p,
    const int* __restrict__ offs,
    const int* __restrict__ csr_src,
    ushort* __restrict__ h_in) {
    const int node = blockIdx.x * 4 + (threadIdx.x >> 6);
    const int l = threadIdx.x & 63;
    const int slice = l >> 4;          // 0..3 edge slot
    const int c = (l & 15) * 8;        // 8 channels per lane
    const int beg = offs[node];
    const int end = offs[node + 1];

    float a0[8], a1[8];
    #pragma unroll
    for (int j = 0; j < 8; ++j) { a0[j] = 0.f; a1[j] = 0.f; }

    int base = beg;
    for (; base + 8 <= end; base += 8) {
        const int sidx = csr_src[base + (l & 7)];
        const int sA = __shfl(sidx, slice, 64);        // edges base+0..3
        const int sB = __shfl(sidx, 4 + slice, 64);    // edges base+4..7
        short8 vA = *reinterpret_cast<const short8*>(xb + (size_t)sA * IN_CH + c);
        short8 vB = *reinterpret_cast<const short8*>(xb + (size_t)sB * IN_CH + c);
        #pragma unroll
        for (int j = 0; j < 8; ++j) {
            a0[j] += b2f((ushort)vA[j]);
            a1[j] += b2f((ushort)vB[j]);
        }
    }
    const int r = end - base;          // 0..7 remainder
    if (r > 0) {
        const int sidx = csr_src[base + min(l & 7, r - 1)];
        const int sA = __shfl(sidx, min(slice, r - 1), 64);
        const int sB = __shfl(sidx, min(4 + slice, r - 1), 64);
        if (slice < r) {
            short8 vA = *reinterpret_cast<const short8*>(xb + (size_t)sA * IN_CH + c);
            #pragma unroll
            for (int j = 0; j < 8; ++j) a0[j] += b2f((ushort)vA[j]);
        }
        if (4 + slice < r) {
            short8 vB = *reinterpret_cast<const short8*>(xb + (size_t)sB * IN_CH + c);
            #pragma unroll
            for (int j = 0; j < 8; ++j) a1[j] += b2f((ushort)vB[j]);
        }
    }

    #pragma unroll
    for (int j = 0; j < 8; ++j) {
        a0[j] += a1[j];
        a0[j] += __shfl_xor(a0[j], 16, 64);
        a0[j] += __shfl_xor(a0[j], 32, 64);
    }

    if (l < 16) {
        const float scale = 1.0f + eps_p[0];
        short8 sv = *reinterpret_cast<const short8*>(xb + (size_t)node * IN_CH + c);
        ushort o[8];
        #pragma unroll
        for (int j = 0; j < 8; ++j)
            o[j] = f2b(scale * b2f((ushort)sv[j]) + a0[j]);
        *reinterpret_cast<short8*>(h_in + (size_t)node * IN_CH + c) =
            *reinterpret_cast<short8*>(o);
    }
}

// ---------------------------------------------------------------------------
// Fused MLP (MFMA): out = log_softmax(relu(relu(h_in@W1+b1)@W2+b2))
// 512 thr = 8 waves x 16 rows. Phase 1 SWAPPED: acc = mfma(W1frag, hfrag)
// -> D[hc][row], lane holds 4 consecutive hc for its row (row = lane&15).
// h1 stays in REGISTERS (bf16 pairs pk[16][2]); a 64-shfl permutation builds
// the phase-2 A-fragments. LDS = 64 KB weights only -> 2 blocks/CU.
// Permutation: lane (n,q), frag kk2, dword i (pair g = 16*kk2+4q+i) pulls
// pk[2*kk2 + (q>>1)][i&1] from lane n + 16*((2q + (i>>1)) & 3).
// ---------------------------------------------------------------------------
__global__ __launch_bounds__(512, 4) void mlp_fused(
    const ushort* __restrict__ h_in,
    const ushort* __restrict__ W1T,
    const ushort* __restrict__ W2T,
    const float* __restrict__ b1,
    const float* __restrict__ b2,
    float* __restrict__ out) {
    __shared__ ushort wbuf[32768];            // 64 KB weights (W1T, then W2T)
    const int t    = threadIdx.x;
    const int w    = t >> 6;
    const int lane = t & 63;
    const int lr   = lane & 15;               // n (row within wave)
    const int lk   = lane >> 4;               // q
    const int row0 = blockIdx.x * 128 + w * 16;
    const int arow = row0 + lr;
    const int arc  = arow < N_NODES ? arow : N_NODES - 1;
    const int sw = (lr & 7) << 3;             // read-side swizzle (halves)

    // ---- stage W1T (rows of 128 halves, swizzled); 64 halves/thread ----
    {
        const ushort* gw = W1T + t * 64;
        const int row = t >> 1;
        const int s = (row & 7) << 3;
        ushort* dstp = wbuf + row * 128;
        #pragma unroll
        for (int j = 0; j < 8; ++j) {
            short8 v = *reinterpret_cast<const short8*>(gw + j * 8);
            const int col = (t & 1) * 64 + j * 8;
            *reinterpret_cast<short8*>(dstp + (col ^ s)) = v;
        }
    }

    // h_in row fragments (phase-1 B operand), row = lr
    short8 a[4];
    const ushort* ap = h_in + (size_t)arc * IN_CH + lk * 8;
    #pragma unroll
    for (int kk = 0; kk < 4; ++kk)
        a[kk] = *reinterpret_cast<const short8*>(ap + kk * 32);

    __syncthreads();

    // ---- phase 1 (swapped): D[hc][row]; lane: row=lr, hc=ct*16+lk*4+r ----
    int pk[16][2];
    #pragma unroll
    for (int ct = 0; ct < 16; ++ct) {
        const ushort* bp = wbuf + (ct * 16 + lr) * 128;
        f32x4 acc = (f32x4){0.f, 0.f, 0.f, 0.f};
        #pragma unroll
        for (int kk = 0; kk < 4; ++kk) {
            short8 wf = *reinterpret_cast<const short8*>(bp + ((lk * 8 + kk * 32) ^ sw));
            acc = __builtin_amdgcn_mfma_f32_16x16x32_bf16(wf, a[kk], acc, 0, 0, 0);
        }
        const float4 bb = *reinterpret_cast<const float4*>(b1 + ct * 16 + lk * 4);
        const float v0 = fmaxf(acc[0] + bb.x, 0.0f);
        const float v1 = fmaxf(acc[1] + bb.y, 0.0f);
        const float v2 = fmaxf(acc[2] + bb.z, 0.0f);
        const float v3 = fmaxf(acc[3] + bb.w, 0.0f);
        pk[ct][0] = (int)f2b(v0) | ((int)f2b(v1) << 16);   // hc pairs 16ct+4lk+{0,1}
        pk[ct][1] = (int)f2b(v2) | ((int)f2b(v3) << 16);   // hc pairs 16ct+4lk+{2,3}
    }

    __syncthreads();   // all waves done reading W1 from wbuf

    // ---- stage W2T (rows of 256 halves, swizzled) ----
    {
        const ushort* gw = W2T + t * 64;
        const int row = t >> 2;
        const int s = (row & 7) << 3;
        ushort* dstp = wbuf + row * 256;
        #pragma unroll
        for (int j = 0; j < 8; ++j) {
            short8 v = *reinterpret_cast<const short8*>(gw + j * 8);
            const int col = (t & 3) * 64 + j * 8;
            *reinterpret_cast<short8*>(dstp + (col ^ s)) = v;
        }
    }

    // ---- in-register permutation: pk -> phase-2 A-frags (h1[row][hc]) ----
    short8 a2[8];
    #pragma unroll
    for (int kk2 = 0; kk2 < 8; ++kk2) {
        const int lo0 = pk[2 * kk2][0],     lo1 = pk[2 * kk2][1];
        const int hi0 = pk[2 * kk2 + 1][0], hi1 = pk[2 * kk2 + 1][1];
        union { int d[4]; short8 s8; } u;
        #pragma unroll
        for (int i = 0; i < 4; ++i) {
            const int srcLane = lr + 16 * ((2 * lk + (i >> 1)) & 3);
            const int vlo = __shfl((i & 1) ? lo1 : lo0, srcLane, 64);
            const int vhi = __shfl((i & 1) ? hi1 : hi0, srcLane, 64);
            u.d[i] = (lk < 2) ? vlo : vhi;
        }
        a2[kk2] = u.s8;
    }

    __syncthreads();   // W2 staged

    // ---- phase 2: out = lsm(relu(h1 @ W2 + b2)), 16 rows x 128 cols ----
    f32x4 acc2[8];
    #pragma unroll
    for (int ct = 0; ct < 8; ++ct) acc2[ct] = (f32x4){0.f, 0.f, 0.f, 0.f};

    #pragma unroll
    for (int ct = 0; ct < 8; ++ct) {
        const ushort* bp = wbuf + (ct * 16 + lr) * 256;
        #pragma unroll
        for (int kk = 0; kk < 8; ++kk) {
            short8 b = *reinterpret_cast<const short8*>(bp + ((lk * 8 + kk * 32) ^ sw));
            acc2[ct] = __builtin_amdgcn_mfma_f32_16x16x32_bf16(a2[kk], b, acc2[ct], 0, 0, 0);
        }
    }

    float bias[8];
    #pragma unroll
    for (int ct = 0; ct < 8; ++ct) bias[ct] = b2[ct * 16 + lr];

    const int orow0 = row0 + lk * 4;
    #pragma unroll
    for (int r = 0; r < 4; ++r) {
        float v[8];
        float m = -1e30f;
        #pragma unroll
        for (int ct = 0; ct < 8; ++ct) {
            v[ct] = fmaxf(acc2[ct][r] + bias[ct], 0.0f);
            m = fmaxf(m, v[ct]);
        }
        #pragma unroll
        for (int o = 1; o < 16; o <<= 1) m = fmaxf(m, __shfl_xor(m, o));
        float s = 0.0f;
        #pragma unroll
        for (int ct = 0; ct < 8; ++ct) s += __expf(v[ct] - m);
        #pragma unroll
        for (int o = 1; o < 16; o <<= 1) s += __shfl_xor(s, o);
        const float lse = m + __logf(s);
        const int orow = orow0 + r;
        if (orow < N_NODES) {
            #pragma unroll
            for (int ct = 0; ct < 8; ++ct)
                out[(size_t)orow * OUT_CH + ct * 16 + lr] = v[ct] - lse;
        }
    }
}

extern "C" void kernel_launch(void* const* d_in, const int* in_sizes, int n_in,
                              void* d_out, int out_size, void* d_ws, size_t ws_size,
                              hipStream_t stream) {
    const float* x    = (const float*)d_in[0];
    const int*   ei   = (const int*)d_in[1];
    const float* W1   = (const float*)d_in[2];
    const float* b1   = (const float*)d_in[3];
    const float* W2   = (const float*)d_in[4];
    const float* b2   = (const float*)d_in[5];
    const float* eps  = (const float*)d_in[6];
    float* out = (float*)d_out;

    // workspace layout
    ushort* xb   = (ushort*)d_ws;                          // 12.8M ushort
    ushort* h_in = xb + (size_t)N_NODES * IN_CH;           // 12.8M
    ushort* W1T  = h_in + (size_t)N_NODES * IN_CH;         // 32768
    ushort* W2T  = W1T + IN_CH * HID_CH;                   // 32768
    int* histT      = (int*)(W2T + HID_CH * OUT_CH);       // NBK*256
    int* blockBaseP = histT + NBK * BIN_BLOCKS;            // NBK*256
    int* bktTotal   = blockBaseP + NBK * BIN_BLOCKS;       // NBK
    int* bktBase    = bktTotal + NBK;                      // NBK
    int* offs       = bktBase + NBK;                       // N_NODES+1
    unsigned int* ebuf = (unsigned int*)(offs + N_NODES + 2); // 1.6M
    int* csr_src    = (int*)(ebuf + N_EDGES);              // 1.6M

    const int* src = ei;
    const int* dst = ei + N_EDGES;

    prep_kernel<<<PREP_TOTAL + BIN_BLOCKS, 256, 0, stream>>>(
        x, W1, W2, dst, xb, W1T, W2T, histT);
    scanA_kernel<<<NBK, 256, 0, stream>>>(histT, blockBaseP, bktTotal);
    scanB_kernel<<<1, 1024, 0, stream>>>(bktTotal, bktBase);
    bin_kernel<<<BIN_BLOCKS, 256, 0, stream>>>(src, dst, blockBaseP, bktBase, ebuf);
    group_kernel<<<NBK, 256, 0, stream>>>(ebuf, bktBase, bktTotal, csr_src, offs);
    gather_kernel<<<N_NODES / 4, 256, 0, stream>>>(xb, eps, offs, csr_src, h_in);
    mlp_fused<<<(N_NODES + 127) / 128, 512, 0, stream>>>(h_in, W1T, W2T, b1, b2, out);
}

// Round 13
// 159.258 us; speedup vs baseline: 1.0650x; 1.0267x over previous
//
#include <hip/hip_runtime.h>

#define N_NODES 100000
#define IN_CH 128
#define HID_CH 256
#define OUT_CH 128
#define N_EDGES 1600000

#define NBK 782                                   // ceil(N_NODES/128) buckets of 128 nodes
#define BIN_BLOCKS 256
#define EPB (N_EDGES / BIN_BLOCKS)                // 6250 edges per bin block
#define BKT_CAP 4096                              // fixed bucket region (mean 2046, z~45)

typedef __attribute__((ext_vector_type(8))) short short8;
typedef __attribute__((ext_vector_type(4))) float f32x4;

// bf16 <-> f32 helpers (bit ops; finite data only)
__device__ __forceinline__ float b2f(ushort u) {
    unsigned int x = ((unsigned int)u) << 16;
    return __uint_as_float(x);
}
__device__ __forceinline__ ushort f2b(float f) {
    unsigned int u = __float_as_uint(f);
    u += 0x7FFFu + ((u >> 16) & 1u);   // round-to-nearest-even
    return (ushort)(u >> 16);
}

// ---------------------------------------------------------------------------
// Prep (+ fused ghist): x fp32 -> xb bf16 ; W1 -> W1T ; W2 -> W2T ;
// last 256 blocks: per-(block,bucket) dst histogram (transposed store).
// ---------------------------------------------------------------------------
#define PREP_X_BLOCKS 6250
#define PREP_W1_BLOCKS 128
#define PREP_W2_BLOCKS 128
#define PREP_TOTAL (PREP_X_BLOCKS + PREP_W1_BLOCKS + PREP_W2_BLOCKS)
__global__ __launch_bounds__(256) void prep_kernel(
    const float* __restrict__ x, const float* __restrict__ W1,
    const float* __restrict__ W2, const int* __restrict__ dst,
    ushort* __restrict__ xb, ushort* __restrict__ W1T,
    ushort* __restrict__ W2T, int* __restrict__ histT) {
    const int b = blockIdx.x;
    const int t = threadIdx.x;
    if (b < PREP_X_BLOCKS) {
        const size_t i = (size_t)b * 2048 + t * 8;
        float4 a = *reinterpret_cast<const float4*>(x + i);
        float4 c = *reinterpret_cast<const float4*>(x + i + 4);
        ushort v[8] = {f2b(a.x), f2b(a.y), f2b(a.z), f2b(a.w),
                       f2b(c.x), f2b(c.y), f2b(c.z), f2b(c.w)};
        *reinterpret_cast<short8*>(xb + i) = *reinterpret_cast<short8*>(v);
    } else if (b < PREP_X_BLOCKS + PREP_W1_BLOCKS) {
        const int i = (b - PREP_X_BLOCKS) * 256 + t;     // oc*128 + k
        const int oc = i >> 7, k = i & 127;
        W1T[i] = f2b(W1[k * HID_CH + oc]);
    } else if (b < PREP_TOTAL) {
        const int i = (b - PREP_X_BLOCKS - PREP_W1_BLOCKS) * 256 + t; // oc*256+k
        const int oc = i >> 8, k = i & 255;
        W2T[i] = f2b(W2[k * OUT_CH + oc]);
    } else {
        __shared__ int h[NBK];
        const int bb = b - PREP_TOTAL;
        for (int k = t; k < NBK; k += 256) h[k] = 0;
        __syncthreads();
        const int base = bb * EPB;
        for (int i = t; i < EPB; i += 256)
            atomicAdd(&h[dst[base + i] >> 7], 1);
        __syncthreads();
        for (int k = t; k < NBK; k += 256) histT[k * BIN_BLOCKS + bb] = h[k];
    }
}

// ---------------------------------------------------------------------------
// Per-bucket exclusive scan over the 256 block counts (no global scan needed:
// bucket regions are fixed at bk*BKT_CAP).
// ---------------------------------------------------------------------------
__global__ __launch_bounds__(256) void scanA_kernel(
    const int* __restrict__ histT, int* __restrict__ blockBaseP,
    int* __restrict__ bktTotal) {
    __shared__ int ts[256];
    const int bk = blockIdx.x, t = threadIdx.x;
    const int v = histT[bk * BIN_BLOCKS + t];
    ts[t] = v;
    __syncthreads();
    #pragma unroll
    for (int o = 1; o < 256; o <<= 1) {
        int add = (t >= o) ? ts[t - o] : 0;
        __syncthreads();
        ts[t] += add;
        __syncthreads();
    }
    blockBaseP[bk * BIN_BLOCKS + t] = ts[t] - v;
    if (t == 255) bktTotal[bk] = ts[255];
}

// ---------------------------------------------------------------------------
// Scatter packed entries (dl<<17 | src) into per-block contiguous runs
// inside each bucket's FIXED region. LDS cursors only.
// ---------------------------------------------------------------------------
__global__ __launch_bounds__(256) void bin_kernel(
    const int* __restrict__ src, const int* __restrict__ dst,
    const int* __restrict__ blockBaseP,
    unsigned int* __restrict__ ebuf) {
    __shared__ int base[NBK];
    __shared__ int cur[NBK];
    const int b = blockIdx.x, t = threadIdx.x;
    for (int k = t; k < NBK; k += 256) {
        base[k] = k * BKT_CAP + blockBaseP[k * BIN_BLOCKS + b];
        cur[k] = 0;
    }
    __syncthreads();
    const int ebase = b * EPB;
    for (int i = t; i < EPB; i += 256) {
        const int d = dst[ebase + i];
        const int s = src[ebase + i];
        const int bk = d >> 7;
        const int r = atomicAdd(&cur[bk], 1);
        ebuf[base[bk] + r] = ((unsigned int)(d & 127) << 17) | (unsigned int)s;
    }
}

// ---------------------------------------------------------------------------
// Node-sort each bucket -> CSR in the fixed region. Writes per-node beg/end.
// ---------------------------------------------------------------------------
__global__ __launch_bounds__(256) void group_kernel(
    const unsigned int* __restrict__ ebuf,
    const int* __restrict__ bktTotal,
    int* __restrict__ csr_src, int* __restrict__ begA, int* __restrict__ endA) {
    __shared__ int hist[128];
    __shared__ int cur[128];
    const int bk = blockIdx.x, t = threadIdx.x;
    if (t < 128) hist[t] = 0;
    __syncthreads();
    const int start = bk * BKT_CAP;
    const int cnt   = bktTotal[bk];
    for (int i = t; i < cnt; i += 256)
        atomicAdd(&hist[ebuf[start + i] >> 17], 1);
    __syncthreads();
    int v = (t < 128) ? hist[t] : 0;
    #pragma unroll
    for (int o = 1; o < 128; o <<= 1) {
        int add = (t < 128 && t >= o) ? hist[t - o] : 0;
        __syncthreads();
        if (t < 128) hist[t] += add;
        __syncthreads();
    }
    if (t < 128) {
        const int excl = hist[t] - v;
        cur[t] = excl;
        const int node = bk * 128 + t;
        if (node < N_NODES) {
            begA[node] = start + excl;
            endA[node] = start + hist[t];   // inclusive scan = end
        }
    }
    __syncthreads();
    for (int i = t; i < cnt; i += 256) {
        const unsigned int e = ebuf[start + i];
        const int dl = e >> 17;
        const int p = atomicAdd(&cur[dl], 1);
        csr_src[start + p] = (int)(e & 0x1FFFF);
    }
}

// ---------------------------------------------------------------------------
// Gather-aggregate fused with GIN self-term (bf16 rows, fp32 accum):
//   h_in[i] = bf16( (1+eps)*x[i] + sum_{j in N(i)} x[j] )
// R8 structure (fastest measured): 8 nodes/block, 32 threads/node, ushort4
// per thread; 32-edge tiles, 4 independent accumulator chains via shfl.
// ---------------------------------------------------------------------------
__global__ __launch_bounds__(256) void gather_kernel(
    const ushort* __restrict__ xb,
    const float* __restrict__ eps_p,
    const int* __restrict__ begA,
    const int* __restrict__ endA,
    const int* __restrict__ csr_src,
    ushort* __restrict__ h_in) {
    const int node = blockIdx.x * 8 + (threadIdx.x >> 5);
    const int l32 = threadIdx.x & 31;
    const int c = l32 * 4;
    const int beg = begA[node];
    const int end = endA[node];

    float4 A0 = {0.f,0.f,0.f,0.f}, A1 = {0.f,0.f,0.f,0.f};
    float4 A2 = {0.f,0.f,0.f,0.f}, A3 = {0.f,0.f,0.f,0.f};

    for (int base = beg; base < end; base += 32) {
        const int nn = min(32, end - base);
        const int sidx = csr_src[base + min(l32, nn - 1)];
        int i = 0;
        for (; i + 4 <= nn; i += 4) {
            const int s0 = __shfl(sidx, i + 0, 32);
            const int s1 = __shfl(sidx, i + 1, 32);
            const int s2 = __shfl(sidx, i + 2, 32);
            const int s3 = __shfl(sidx, i + 3, 32);
            ushort4 v0 = *reinterpret_cast<const ushort4*>(xb + (size_t)s0 * IN_CH + c);
            ushort4 v1 = *reinterpret_cast<const ushort4*>(xb + (size_t)s1 * IN_CH + c);
            ushort4 v2 = *reinterpret_cast<const ushort4*>(xb + (size_t)s2 * IN_CH + c);
            ushort4 v3 = *reinterpret_cast<const ushort4*>(xb + (size_t)s3 * IN_CH + c);
            A0.x += b2f(v0.x); A0.y += b2f(v0.y); A0.z += b2f(v0.z); A0.w += b2f(v0.w);
            A1.x += b2f(v1.x); A1.y += b2f(v1.y); A1.z += b2f(v1.z); A1.w += b2f(v1.w);
            A2.x += b2f(v2.x); A2.y += b2f(v2.y); A2.z += b2f(v2.z); A2.w += b2f(v2.w);
            A3.x += b2f(v3.x); A3.y += b2f(v3.y); A3.z += b2f(v3.z); A3.w += b2f(v3.w);
        }
        for (; i < nn; ++i) {
            const int s = __shfl(sidx, i, 32);
            ushort4 v = *reinterpret_cast<const ushort4*>(xb + (size_t)s * IN_CH + c);
            A0.x += b2f(v.x); A0.y += b2f(v.y); A0.z += b2f(v.z); A0.w += b2f(v.w);
        }
    }

    const float a0 = A0.x + A1.x + A2.x + A3.x;
    const float a1 = A0.y + A1.y + A2.y + A3.y;
    const float a2 = A0.z + A1.z + A2.z + A3.z;
    const float a3 = A0.w + A1.w + A2.w + A3.w;

    const float scale = 1.0f + eps_p[0];
    ushort4 sv = *reinterpret_cast<const ushort4*>(xb + (size_t)node * IN_CH + c);
    ushort4 o;
    o.x = f2b(scale * b2f(sv.x) + a0);
    o.y = f2b(scale * b2f(sv.y) + a1);
    o.z = f2b(scale * b2f(sv.z) + a2);
    o.w = f2b(scale * b2f(sv.w) + a3);
    *reinterpret_cast<ushort4*>(h_in + (size_t)node * IN_CH + c) = o;
}

// ---------------------------------------------------------------------------
// Fused MLP (MFMA): out = log_softmax(relu(relu(h_in@W1+b1)@W2+b2))
// 512 thr = 8 waves x 16 rows. Phase 1 SWAPPED: acc = mfma(W1frag, hfrag)
// -> D[hc][row]; h1 stays in registers; 64-shfl permutation builds phase-2
// A-frags. LDS = 64 KB weights only -> 2 blocks/CU.
// ---------------------------------------------------------------------------
__global__ __launch_bounds__(512, 4) void mlp_fused(
    const ushort* __restrict__ h_in,
    const ushort* __restrict__ W1T,
    const ushort* __restrict__ W2T,
    const float* __restrict__ b1,
    const float* __restrict__ b2,
    float* __restrict__ out) {
    __shared__ ushort wbuf[32768];            // 64 KB weights (W1T, then W2T)
    const int t    = threadIdx.x;
    const int w    = t >> 6;
    const int lane = t & 63;
    const int lr   = lane & 15;               // n (row within wave)
    const int lk   = lane >> 4;               // q
    const int row0 = blockIdx.x * 128 + w * 16;
    const int arow = row0 + lr;
    const int arc  = arow < N_NODES ? arow : N_NODES - 1;
    const int sw = (lr & 7) << 3;             // read-side swizzle (halves)

    // ---- stage W1T (rows of 128 halves, swizzled); 64 halves/thread ----
    {
        const ushort* gw = W1T + t * 64;
        const int row = t >> 1;
        const int s = (row & 7) << 3;
        ushort* dstp = wbuf + row * 128;
        #pragma unroll
        for (int j = 0; j < 8; ++j) {
            short8 v = *reinterpret_cast<const short8*>(gw + j * 8);
            const int col = (t & 1) * 64 + j * 8;
            *reinterpret_cast<short8*>(dstp + (col ^ s)) = v;
        }
    }

    // h_in row fragments (phase-1 B operand), row = lr
    short8 a[4];
    const ushort* ap = h_in + (size_t)arc * IN_CH + lk * 8;
    #pragma unroll
    for (int kk = 0; kk < 4; ++kk)
        a[kk] = *reinterpret_cast<const short8*>(ap + kk * 32);

    __syncthreads();

    // ---- phase 1 (swapped): D[hc][row]; lane: row=lr, hc=ct*16+lk*4+r ----
    int pk[16][2];
    #pragma unroll
    for (int ct = 0; ct < 16; ++ct) {
        const ushort* bp = wbuf + (ct * 16 + lr) * 128;
        f32x4 acc = (f32x4){0.f, 0.f, 0.f, 0.f};
        #pragma unroll
        for (int kk = 0; kk < 4; ++kk) {
            short8 wf = *reinterpret_cast<const short8*>(bp + ((lk * 8 + kk * 32) ^ sw));
            acc = __builtin_amdgcn_mfma_f32_16x16x32_bf16(wf, a[kk], acc, 0, 0, 0);
        }
        const float4 bb = *reinterpret_cast<const float4*>(b1 + ct * 16 + lk * 4);
        const float v0 = fmaxf(acc[0] + bb.x, 0.0f);
        const float v1 = fmaxf(acc[1] + bb.y, 0.0f);
        const float v2 = fmaxf(acc[2] + bb.z, 0.0f);
        const float v3 = fmaxf(acc[3] + bb.w, 0.0f);
        pk[ct][0] = (int)f2b(v0) | ((int)f2b(v1) << 16);
        pk[ct][1] = (int)f2b(v2) | ((int)f2b(v3) << 16);
    }

    __syncthreads();   // all waves done reading W1 from wbuf

    // ---- stage W2T (rows of 256 halves, swizzled) ----
    {
        const ushort* gw = W2T + t * 64;
        const int row = t >> 2;
        const int s = (row & 7) << 3;
        ushort* dstp = wbuf + row * 256;
        #pragma unroll
        for (int j = 0; j < 8; ++j) {
            short8 v = *reinterpret_cast<const short8*>(gw + j * 8);
            const int col = (t & 3) * 64 + j * 8;
            *reinterpret_cast<short8*>(dstp + (col ^ s)) = v;
        }
    }

    // ---- in-register permutation: pk -> phase-2 A-frags (h1[row][hc]) ----
    short8 a2[8];
    #pragma unroll
    for (int kk2 = 0; kk2 < 8; ++kk2) {
        const int lo0 = pk[2 * kk2][0],     lo1 = pk[2 * kk2][1];
        const int hi0 = pk[2 * kk2 + 1][0], hi1 = pk[2 * kk2 + 1][1];
        union { int d[4]; short8 s8; } u;
        #pragma unroll
        for (int i = 0; i < 4; ++i) {
            const int srcLane = lr + 16 * ((2 * lk + (i >> 1)) & 3);
            const int vlo = __shfl((i & 1) ? lo1 : lo0, srcLane, 64);
            const int vhi = __shfl((i & 1) ? hi1 : hi0, srcLane, 64);
            u.d[i] = (lk < 2) ? vlo : vhi;
        }
        a2[kk2] = u.s8;
    }

    __syncthreads();   // W2 staged

    // ---- phase 2: out = lsm(relu(h1 @ W2 + b2)), 16 rows x 128 cols ----
    f32x4 acc2[8];
    #pragma unroll
    for (int ct = 0; ct < 8; ++ct) acc2[ct] = (f32x4){0.f, 0.f, 0.f, 0.f};

    #pragma unroll
    for (int ct = 0; ct < 8; ++ct) {
        const ushort* bp = wbuf + (ct * 16 + lr) * 256;
        #pragma unroll
        for (int kk = 0; kk < 8; ++kk) {
            short8 b = *reinterpret_cast<const short8*>(bp + ((lk * 8 + kk * 32) ^ sw));
            acc2[ct] = __builtin_amdgcn_mfma_f32_16x16x32_bf16(a2[kk], b, acc2[ct], 0, 0, 0);
        }
    }

    float bias[8];
    #pragma unroll
    for (int ct = 0; ct < 8; ++ct) bias[ct] = b2[ct * 16 + lr];

    const int orow0 = row0 + lk * 4;
    #pragma unroll
    for (int r = 0; r < 4; ++r) {
        float v[8];
        float m = -1e30f;
        #pragma unroll
        for (int ct = 0; ct < 8; ++ct) {
            v[ct] = fmaxf(acc2[ct][r] + bias[ct], 0.0f);
            m = fmaxf(m, v[ct]);
        }
        #pragma unroll
        for (int o = 1; o < 16; o <<= 1) m = fmaxf(m, __shfl_xor(m, o));
        float s = 0.0f;
        #pragma unroll
        for (int ct = 0; ct < 8; ++ct) s += __expf(v[ct] - m);
        #pragma unroll
        for (int o = 1; o < 16; o <<= 1) s += __shfl_xor(s, o);
        const float lse = m + __logf(s);
        const int orow = orow0 + r;
        if (orow < N_NODES) {
            #pragma unroll
            for (int ct = 0; ct < 8; ++ct)
                out[(size_t)orow * OUT_CH + ct * 16 + lr] = v[ct] - lse;
        }
    }
}

extern "C" void kernel_launch(void* const* d_in, const int* in_sizes, int n_in,
                              void* d_out, int out_size, void* d_ws, size_t ws_size,
                              hipStream_t stream) {
    const float* x    = (const float*)d_in[0];
    const int*   ei   = (const int*)d_in[1];
    const float* W1   = (const float*)d_in[2];
    const float* b1   = (const float*)d_in[3];
    const float* W2   = (const float*)d_in[4];
    const float* b2   = (const float*)d_in[5];
    const float* eps  = (const float*)d_in[6];
    float* out = (float*)d_out;

    // workspace layout
    ushort* xb   = (ushort*)d_ws;                          // 12.8M ushort
    ushort* h_in = xb + (size_t)N_NODES * IN_CH;           // 12.8M
    ushort* W1T  = h_in + (size_t)N_NODES * IN_CH;         // 32768
    ushort* W2T  = W1T + IN_CH * HID_CH;                   // 32768
    int* histT      = (int*)(W2T + HID_CH * OUT_CH);       // NBK*256
    int* blockBaseP = histT + NBK * BIN_BLOCKS;            // NBK*256
    int* bktTotal   = blockBaseP + NBK * BIN_BLOCKS;       // NBK
    int* begA       = bktTotal + NBK;                      // N_NODES
    int* endA       = begA + N_NODES;                      // N_NODES
    unsigned int* ebuf = (unsigned int*)(endA + N_NODES);  // NBK*BKT_CAP (12.8 MB)
    int* csr_src    = (int*)(ebuf + (size_t)NBK * BKT_CAP); // NBK*BKT_CAP (12.8 MB)

    const int* src = ei;
    const int* dst = ei + N_EDGES;

    prep_kernel<<<PREP_TOTAL + BIN_BLOCKS, 256, 0, stream>>>(
        x, W1, W2, dst, xb, W1T, W2T, histT);
    scanA_kernel<<<NBK, 256, 0, stream>>>(histT, blockBaseP, bktTotal);
    bin_kernel<<<BIN_BLOCKS, 256, 0, stream>>>(src, dst, blockBaseP, ebuf);
    group_kernel<<<NBK, 256, 0, stream>>>(ebuf, bktTotal, csr_src, begA, endA);
    gather_kernel<<<N_NODES / 8, 256, 0, stream>>>(xb, eps, begA, endA, csr_src, h_in);
    mlp_fused<<<(N_NODES + 127) / 128, 512, 0, stream>>>(h_in, W1T, W2T, b1, b2, out);
}